// Round 14
// baseline (710.214 us; speedup 1.0000x reference)
//
#include <hip/hip_runtime.h>
#include <hip/hip_bf16.h>
#include <math.h>

#define B 1024
#define D 512
#define KC 100000
#define MARGIN 0.3f
#define EPSSM 0.1f
#define NCP 782          // ceil(KC/128) column panels
#define NCP_PAD 784

typedef __attribute__((ext_vector_type(8))) short bf16x8;
typedef __attribute__((ext_vector_type(4))) float f32x4;

__device__ __forceinline__ unsigned cvtpk(float lo, float hi) {
    union { __hip_bfloat162 h2; unsigned u; } cv;
    cv.h2 = __float22bfloat162_rn(make_float2(lo, hi));
    return cv.u;
}

__device__ __forceinline__ void async16(const void* g, void* l) {
    __builtin_amdgcn_global_load_lds((const __attribute__((address_space(1))) unsigned int*)g,
                                     (__attribute__((address_space(3))) unsigned int*)l,
                                     16, 0, 0);
}

#define VMCNT(n) asm volatile("s_waitcnt vmcnt(" #n ")" ::: "memory")
#define LGKM0    asm volatile("s_waitcnt lgkmcnt(0)" ::: "memory")
#define FENCE    asm volatile("" ::: "memory")

// ws float layout: [0,B) sumexp | [B,2B) lin | [2B,3B) apbits | [3B,4B) anbits
// xp (packed bf16 x) at byte 16384: 64 regions x 16KB = 1MB.

__global__ void init_ws(float* ws) {
    int i = blockIdx.x * blockDim.x + threadIdx.x;
    if (i < 2 * B) ws[i] = 0.f;
    else if (i < 3 * B) ((int*)ws)[i] = 0;
    else if (i < 4 * B) ((int*)ws)[i] = 0x7F800000;
}

// ===== PREP: triplet[0,256) + tlabel[256,512) + pack_x[512,768) =====
__global__ __launch_bounds__(256) void prep_kernel(const float* __restrict__ x,
                                                   const float* __restrict__ W,
                                                   const float* __restrict__ bias,
                                                   const int* __restrict__ labels,
                                                   float* __restrict__ ws,
                                                   unsigned short* __restrict__ xp) {
    const int bid = blockIdx.x;
    const int tid = threadIdx.x;
    __shared__ float xs[8][D];
    __shared__ int labs[8];
    __shared__ float sqi[8];
    __shared__ float red_ap[8][4], red_an[8][4];

    if (bid >= 512) {
        // pack_x: region (mb*16+kt) = 16KB = [256 rows][4 units of 8 bf16],
        // data unit ku stored at pos qpos = ku ^ ((rloc>>1)&3)  (baked swizzle)
        int gid = (bid - 512) * 256 + tid;       // 64 regions * 1024 units
        int region = gid >> 10;
        int p = gid & 1023;
        int rloc = p >> 2, qpos = p & 3;
        int ku = qpos ^ ((rloc >> 1) & 3);
        int mb = region >> 4, kt = region & 15;
        const float* src = x + (size_t)(mb * 256 + rloc) * D + kt * 32 + ku * 8;
        f32x4 a = *(const f32x4*)src;
        f32x4 b2 = *(const f32x4*)(src + 4);
        unsigned pv[4] = { cvtpk(a[0], a[1]), cvtpk(a[2], a[3]), cvtpk(b2[0], b2[1]), cvtpk(b2[2], b2[3]) };
        *(uint4*)(xp + (size_t)region * 8192 + (size_t)p * 8) = *(uint4*)pv;
        return;
    }
    if (bid >= 256) {
        // tlabel -> lin += 0.9*(x.Wlab + blab)
        int wid = tid >> 6, lane = tid & 63;
        int row = (bid - 256) * 4 + wid;
        int lab = labels[row];
        const float* xr = x + (size_t)row * D;
        const float* wr = W + (size_t)lab * D;
        float dsum = 0.f;
#pragma unroll
        for (int u = 0; u < 2; ++u) {
            int k = (lane * 2 + u) * 4;
            float4 a = *(const float4*)&xr[k];
            float4 w = *(const float4*)&wr[k];
            dsum += a.x * w.x + a.y * w.y + a.z * w.z + a.w * w.w;
        }
        for (int o = 32; o >= 1; o >>= 1) dsum += __shfl_xor(dsum, o);
        if (lane == 0) atomicAdd(&ws[B + row], (1.f - EPSSM) * (dsum + bias[lab]));
        return;
    }

    // triplet: batch-hard over a 512-j half, atomic bitwise max/min merge
    const int row0 = (bid >> 1) * 8;
    const int jbase = (bid & 1) * 512;
    for (int f = tid; f < 8 * (D / 4); f += 256) {
        int r = f / (D / 4);
        int p = f % (D / 4);
        *(float4*)&xs[r][p * 4] = *(const float4*)&x[(size_t)(row0 + r) * D + p * 4];
    }
    if (tid < 8) labs[tid] = labels[row0 + tid];
    __syncthreads();
    if (tid < 8) {
        float s = 0.f;
        for (int k = 0; k < D; ++k) s += xs[tid][k] * xs[tid][k];
        sqi[tid] = s;
    }
    __syncthreads();

    float ap[8], an[8];
#pragma unroll
    for (int r = 0; r < 8; ++r) { ap[r] = -INFINITY; an[r] = INFINITY; }

    for (int j = jbase + tid; j < jbase + 512; j += 256) {
        int labj = labels[j];
        float dot[8];
        float sqj = 0.f;
#pragma unroll
        for (int r = 0; r < 8; ++r) dot[r] = 0.f;
        for (int kc = 0; kc < D; kc += 32) {
            float4 xj[8];
#pragma unroll
            for (int u = 0; u < 8; ++u) xj[u] = *(const float4*)&x[(size_t)j * D + kc + u * 4];
#pragma unroll
            for (int u = 0; u < 8; ++u)
                sqj += xj[u].x * xj[u].x + xj[u].y * xj[u].y + xj[u].z * xj[u].z + xj[u].w * xj[u].w;
#pragma unroll
            for (int r = 0; r < 8; ++r) {
                float d = 0.f;
#pragma unroll
                for (int u = 0; u < 8; ++u) {
                    const float4 a = *(const float4*)&xs[r][kc + u * 4];
                    d += a.x * xj[u].x + a.y * xj[u].y + a.z * xj[u].z + a.w * xj[u].w;
                }
                dot[r] += d;
            }
        }
#pragma unroll
        for (int r = 0; r < 8; ++r) {
            float d2 = sqi[r] + sqj - 2.f * dot[r];
            float dist = sqrtf(fmaxf(d2, 1e-12f));
            if (labj == labs[r]) ap[r] = fmaxf(ap[r], dist);
            else an[r] = fminf(an[r], dist);
        }
    }
#pragma unroll
    for (int r = 0; r < 8; ++r) {
        for (int o = 32; o >= 1; o >>= 1) {
            ap[r] = fmaxf(ap[r], __shfl_xor(ap[r], o));
            an[r] = fminf(an[r], __shfl_xor(an[r], o));
        }
    }
    int wid = tid >> 6;
    if ((tid & 63) == 0) {
#pragma unroll
        for (int r = 0; r < 8; ++r) { red_ap[r][wid] = ap[r]; red_an[r][wid] = an[r]; }
    }
    __syncthreads();
    if (tid < 8) {
        float a = -INFINITY, n = INFINITY;
#pragma unroll
        for (int w = 0; w < 4; ++w) { a = fmaxf(a, red_ap[tid][w]); n = fminf(n, red_an[tid][w]); }
        a = fmaxf(a, 0.f);
        int* apbits = (int*)(ws + 2 * B);
        int* anbits = (int*)(ws + 3 * B);
        atomicMax(&apbits[row0 + tid], __float_as_int(a));
        atomicMin(&anbits[row0 + tid], __float_as_int(n));
    }
}

// ===== 256x128xBK32 GEMM, 3 blocks/CU, 1 barrier/phase =====
// 256 thr, 4 waves (2Mx2N; wave tile 128x64). LDS 48KB: A 2 slots x 16KB (gload_lds,
// linear src, depth-1 prefetch -- xp is L2-resident so 1-phase wait is cheap) +
// B 2 parities x 8KB (reg-staged depth-3 from fp32 W: coalesced dwordx4 -> cvtpk ->
// swizzled ds_write one phase ahead into opposite parity). Strict parity separation
// makes ONE barrier/phase sound; VMCNT precedes barrier (per-wave DMA completeness).
// In-order ledger (issue A(kt+1) then B(kt+3) right after barrier):
//   kt=0: VMCNT(8); 1<=kt<=13: VMCNT(4); kt>=14: VMCNT(0).
__global__ __launch_bounds__(256, 3) void ce_gemm_r3(const unsigned short* __restrict__ xp,
                                                     const float* __restrict__ W,
                                                     const float* __restrict__ bias,
                                                     float* __restrict__ ws) {
    const int b = blockIdx.x;
    const int xcd = b & 7, slot = b >> 3;
    const int cp = (slot >> 2) * 8 + xcd;   // column panel (128 cols)
    const int mb = slot & 3;                // row block (256 rows)
    if (cp >= NCP) return;
    const int rowbase = mb * 256;
    const int cbase = cp * 128;

    __shared__ unsigned short lds[24576];   // 48KB: A slots s*8192 (s=0,1); B at 16384 + p*4096

    const int tid = threadIdx.x;
    const int lane = tid & 63;
    const int wid = tid >> 6;
    const int wm = wid >> 1, wn = wid & 1;  // wave tile 128 rows x 64 cols
    const int q = lane >> 4, l15 = lane & 15;

    // B staging geometry: thread -> (col-class rB, 16-float half)
    const int rB = tid >> 1;
    const int ku0 = (tid & 1) * 2;
    const int swB = (rB >> 1) & 3;
    const int p0 = rB * 4 + (ku0 ^ swB);
    const int p1 = rB * 4 + ((ku0 + 1) ^ swB);
    int rc = cbase + rB; rc = rc < KC ? rc : KC - 1;
    const float* pW = W + (size_t)rc * D + (tid & 1) * 16;

    f32x4 acc[8][4];
#pragma unroll
    for (int m = 0; m < 8; ++m)
#pragma unroll
        for (int n = 0; n < 4; ++n) acc[m][n] = (f32x4){0.f, 0.f, 0.f, 0.f};

    f32x4 bsv[3][4];   // 3 reg-sets x 16 floats (static indexing via unrolled kt)

#define BLOAD(s_, kt_) {                                                           \
        _Pragma("unroll") for (int j = 0; j < 4; ++j)                              \
            bsv[s_][j] = *(const f32x4*)(pW + (kt_) * 32 + j * 4);                 \
        FENCE; }
#define ALOAD(kt_) {                                                               \
        const unsigned short* ga = xp + (size_t)(mb * 16 + (kt_)) * 8192;          \
        unsigned short* lA = &lds[((kt_) & 1) * 8192];                             \
        _Pragma("unroll") for (int i = 0; i < 4; ++i)                              \
            async16(ga + (i * 256 + tid) * 8, lA + (i * 256 + tid) * 8);           \
        FENCE; }
#define BCVW(s_, kt_) {                                                            \
        unsigned short* lB = &lds[16384 + ((kt_) & 1) * 4096];                     \
        unsigned u0[4] = { cvtpk(bsv[s_][0][0], bsv[s_][0][1]),                    \
                           cvtpk(bsv[s_][0][2], bsv[s_][0][3]),                    \
                           cvtpk(bsv[s_][1][0], bsv[s_][1][1]),                    \
                           cvtpk(bsv[s_][1][2], bsv[s_][1][3]) };                  \
        unsigned u1[4] = { cvtpk(bsv[s_][2][0], bsv[s_][2][1]),                    \
                           cvtpk(bsv[s_][2][2], bsv[s_][2][3]),                    \
                           cvtpk(bsv[s_][3][0], bsv[s_][3][1]),                    \
                           cvtpk(bsv[s_][3][2], bsv[s_][3][3]) };                  \
        *(uint4*)&lB[p0 * 8] = *(uint4*)u0;                                        \
        *(uint4*)&lB[p1 * 8] = *(uint4*)u1; }

    // prologue: A(0); B regs 0..2; wait A0+B0; write B(0) parity 0
    ALOAD(0);
    BLOAD(0, 0); BLOAD(1, 1); BLOAD(2, 2);
    VMCNT(8);             // in-order: A0,B0 complete (B1,B2 may float)
    BCVW(0, 0);
    LGKM0;

    bf16x8 af[4], bfr[4];
#pragma unroll
    for (int kt = 0; kt < 16; ++kt) {
        if (kt == 0) { VMCNT(8); } else if (kt <= 13) { VMCNT(4); } else { VMCNT(0); }
        __builtin_amdgcn_s_barrier(); FENCE;

        // issue next-phase loads immediately (max issue-to-wait distance)
        if (kt <= 14) ALOAD(kt + 1);
        if (kt <= 12) BLOAD((kt + 3) % 3, kt + 3);

        const unsigned short* sA = &lds[(kt & 1) * 8192];
        const unsigned short* sB = &lds[16384 + (kt & 1) * 4096];
#pragma unroll
        for (int n = 0; n < 4; ++n) {
            int rl = wn * 64 + n * 16 + l15;
            bfr[n] = *(const bf16x8*)&sB[(rl * 4 + (q ^ ((rl >> 1) & 3))) * 8];
        }
#pragma unroll
        for (int mg = 0; mg < 2; ++mg) {
#pragma unroll
            for (int mf = 0; mf < 4; ++mf) {
                int rl = wm * 128 + (mg * 4 + mf) * 16 + l15;
                af[mf] = *(const bf16x8*)&sA[(rl * 4 + (q ^ ((rl >> 1) & 3))) * 8];
            }
            __builtin_amdgcn_s_setprio(1);
#pragma unroll
            for (int mf = 0; mf < 4; ++mf)
#pragma unroll
                for (int n = 0; n < 4; ++n)
                    acc[mg * 4 + mf][n] = __builtin_amdgcn_mfma_f32_16x16x32_bf16(
                        af[mf], bfr[n], acc[mg * 4 + mf][n], 0, 0, 0);
            __builtin_amdgcn_s_setprio(0);
        }

        if (kt <= 14) BCVW((kt + 1) % 3, kt + 1);   // write next B into opposite parity
        LGKM0;                                      // ds_writes visible before next barrier
    }
#undef BLOAD
#undef ALOAD
#undef BCVW

    // ---- epilogue: per-row sum(exp)/sum(logit); shfl over l15; [256][2] LDS; atomics ----
    __syncthreads();
    float* redE = (float*)lds;           // [256][2]
    float* redL = redE + 512;            // [256][2]
    float biasv[4];
#pragma unroll
    for (int n = 0; n < 4; ++n) {
        int cc = cbase + wn * 64 + n * 16 + l15;
        biasv[n] = bias[cc < KC ? cc : KC - 1];
    }
#pragma unroll
    for (int m = 0; m < 8; ++m) {
#pragma unroll
        for (int r2 = 0; r2 < 4; ++r2) {
            float pe = 0.f, pl = 0.f;
#pragma unroll
            for (int n = 0; n < 4; ++n) {
                int cc = cbase + wn * 64 + n * 16 + l15;
                if (cc < KC) {
                    float lg = acc[m][n][r2] + biasv[n];
                    pe += __expf(lg);
                    pl += lg;
                }
            }
#pragma unroll
            for (int o = 1; o < 16; o <<= 1) {
                pe += __shfl_xor(pe, o);
                pl += __shfl_xor(pl, o);
            }
            if (l15 == 0) {
                int rowl = wm * 128 + m * 16 + q * 4 + r2;
                redE[rowl * 2 + wn] = pe;
                redL[rowl * 2 + wn] = pl;
            }
        }
    }
    __syncthreads();
    if (tid < 256) {
        float se = redE[tid * 2] + redE[tid * 2 + 1];
        float sl = redL[tid * 2] + redL[tid * 2 + 1];
        atomicAdd(&ws[rowbase + tid], se);
        atomicAdd(&ws[B + rowbase + tid], (EPSSM / (float)KC) * sl);
    }
}

// ---------------- final combine ----------------
__global__ __launch_bounds__(1024) void final_kernel(const float* __restrict__ ws,
                                                     float* __restrict__ out) {
    const float* sumexp = ws;
    const float* lin = ws + B;
    const int* apbits = (const int*)(ws + 2 * B);
    const int* anbits = (const int*)(ws + 3 * B);
    int i = threadIdx.x;
    float ce = logf(sumexp[i]) - lin[i];
    float ap = __int_as_float(apbits[i]);
    float an = __int_as_float(anbits[i]);
    float v = ce + fmaxf(ap - an + MARGIN, 0.f);
    for (int o = 32; o >= 1; o >>= 1) v += __shfl_xor(v, o);
    __shared__ float red[16];
    int wid = threadIdx.x >> 6, lane = threadIdx.x & 63;
    if (lane == 0) red[wid] = v;
    __syncthreads();
    if (threadIdx.x == 0) {
        float s = 0.f;
#pragma unroll
        for (int w = 0; w < 16; ++w) s += red[w];
        out[0] = s / (float)B;
    }
}

extern "C" void kernel_launch(void* const* d_in, const int* in_sizes, int n_in,
                              void* d_out, int out_size, void* d_ws, size_t ws_size,
                              hipStream_t stream) {
    const float* x = (const float*)d_in[0];
    const float* W = (const float*)d_in[1];
    const float* bias = (const float*)d_in[2];
    const int* labels = (const int*)d_in[3];
    float* out = (float*)d_out;
    float* ws = (float*)d_ws;

    unsigned short* xp = (unsigned short*)((char*)d_ws + 16384);   // 1MB packed x

    init_ws<<<16, 256, 0, stream>>>(ws);
    prep_kernel<<<768, 256, 0, stream>>>(x, W, bias, labels, ws, xp);
    ce_gemm_r3<<<8 * (NCP_PAD / 8) * 4, 256, 0, stream>>>(xp, W, bias, ws);
    final_kernel<<<1, 1024, 0, stream>>>(ws, out);
}

// Round 15
// 225.898 us; speedup vs baseline: 3.1440x; 3.1440x over previous
//
#include <hip/hip_runtime.h>
#include <hip/hip_bf16.h>
#include <math.h>

#define B 1024
#define D 512
#define KC 100000
#define MARGIN 0.3f
#define EPSSM 0.1f
#define NCP 782          // ceil(KC/128) column panels
#define NCP_PAD 784

typedef __attribute__((ext_vector_type(8))) short bf16x8;
typedef __attribute__((ext_vector_type(4))) float f32x4;

__device__ __forceinline__ unsigned cvtpk(float lo, float hi) {
    union { __hip_bfloat162 h2; unsigned u; } cv;
    cv.h2 = __float22bfloat162_rn(make_float2(lo, hi));
    return cv.u;
}

__device__ __forceinline__ void async16(const void* g, void* l) {
    __builtin_amdgcn_global_load_lds((const __attribute__((address_space(1))) unsigned int*)g,
                                     (__attribute__((address_space(3))) unsigned int*)l,
                                     16, 0, 0);
}

#define VMCNT(n) asm volatile("s_waitcnt vmcnt(" #n ")" ::: "memory")
#define LGKM0    asm volatile("s_waitcnt lgkmcnt(0)" ::: "memory")
#define FENCE    asm volatile("" ::: "memory")

// ws float layout: [0,B) sumexp | [B,2B) lin | [2B,3B) apbits | [3B,4B) anbits
// xp (packed bf16 x) at byte 16384: 64 regions x 16KB = 1MB.

__global__ void init_ws(float* ws) {
    int i = blockIdx.x * blockDim.x + threadIdx.x;
    if (i < 2 * B) ws[i] = 0.f;
    else if (i < 3 * B) ((int*)ws)[i] = 0;
    else if (i < 4 * B) ((int*)ws)[i] = 0x7F800000;
}

// ===== PREP: triplet[0,256) + tlabel[256,512) + pack_x[512,768) =====
__global__ __launch_bounds__(256) void prep_kernel(const float* __restrict__ x,
                                                   const float* __restrict__ W,
                                                   const float* __restrict__ bias,
                                                   const int* __restrict__ labels,
                                                   float* __restrict__ ws,
                                                   unsigned short* __restrict__ xp) {
    const int bid = blockIdx.x;
    const int tid = threadIdx.x;
    __shared__ float xs[8][D];
    __shared__ int labs[8];
    __shared__ float sqi[8];
    __shared__ float red_ap[8][4], red_an[8][4];

    if (bid >= 512) {
        // pack_x: region (mb*16+kt) = 16KB = [256 rows][4 units of 8 bf16],
        // data unit ku stored at pos qpos = ku ^ ((rloc>>1)&3)  (baked swizzle)
        int gid = (bid - 512) * 256 + tid;       // 64 regions * 1024 units
        int region = gid >> 10;
        int p = gid & 1023;
        int rloc = p >> 2, qpos = p & 3;
        int ku = qpos ^ ((rloc >> 1) & 3);
        int mb = region >> 4, kt = region & 15;
        const float* src = x + (size_t)(mb * 256 + rloc) * D + kt * 32 + ku * 8;
        f32x4 a = *(const f32x4*)src;
        f32x4 b2 = *(const f32x4*)(src + 4);
        unsigned pv[4] = { cvtpk(a[0], a[1]), cvtpk(a[2], a[3]), cvtpk(b2[0], b2[1]), cvtpk(b2[2], b2[3]) };
        *(uint4*)(xp + (size_t)region * 8192 + (size_t)p * 8) = *(uint4*)pv;
        return;
    }
    if (bid >= 256) {
        // tlabel -> lin += 0.9*(x.Wlab + blab)
        int wid = tid >> 6, lane = tid & 63;
        int row = (bid - 256) * 4 + wid;
        int lab = labels[row];
        const float* xr = x + (size_t)row * D;
        const float* wr = W + (size_t)lab * D;
        float dsum = 0.f;
#pragma unroll
        for (int u = 0; u < 2; ++u) {
            int k = (lane * 2 + u) * 4;
            float4 a = *(const float4*)&xr[k];
            float4 w = *(const float4*)&wr[k];
            dsum += a.x * w.x + a.y * w.y + a.z * w.z + a.w * w.w;
        }
        for (int o = 32; o >= 1; o >>= 1) dsum += __shfl_xor(dsum, o);
        if (lane == 0) atomicAdd(&ws[B + row], (1.f - EPSSM) * (dsum + bias[lab]));
        return;
    }

    // triplet: batch-hard over a 512-j half, atomic bitwise max/min merge
    const int row0 = (bid >> 1) * 8;
    const int jbase = (bid & 1) * 512;
    for (int f = tid; f < 8 * (D / 4); f += 256) {
        int r = f / (D / 4);
        int p = f % (D / 4);
        *(float4*)&xs[r][p * 4] = *(const float4*)&x[(size_t)(row0 + r) * D + p * 4];
    }
    if (tid < 8) labs[tid] = labels[row0 + tid];
    __syncthreads();
    if (tid < 8) {
        float s = 0.f;
        for (int k = 0; k < D; ++k) s += xs[tid][k] * xs[tid][k];
        sqi[tid] = s;
    }
    __syncthreads();

    float ap[8], an[8];
#pragma unroll
    for (int r = 0; r < 8; ++r) { ap[r] = -INFINITY; an[r] = INFINITY; }

    for (int j = jbase + tid; j < jbase + 512; j += 256) {
        int labj = labels[j];
        float dot[8];
        float sqj = 0.f;
#pragma unroll
        for (int r = 0; r < 8; ++r) dot[r] = 0.f;
        for (int kc = 0; kc < D; kc += 32) {
            float4 xj[8];
#pragma unroll
            for (int u = 0; u < 8; ++u) xj[u] = *(const float4*)&x[(size_t)j * D + kc + u * 4];
#pragma unroll
            for (int u = 0; u < 8; ++u)
                sqj += xj[u].x * xj[u].x + xj[u].y * xj[u].y + xj[u].z * xj[u].z + xj[u].w * xj[u].w;
#pragma unroll
            for (int r = 0; r < 8; ++r) {
                float d = 0.f;
#pragma unroll
                for (int u = 0; u < 8; ++u) {
                    const float4 a = *(const float4*)&xs[r][kc + u * 4];
                    d += a.x * xj[u].x + a.y * xj[u].y + a.z * xj[u].z + a.w * xj[u].w;
                }
                dot[r] += d;
            }
        }
#pragma unroll
        for (int r = 0; r < 8; ++r) {
            float d2 = sqi[r] + sqj - 2.f * dot[r];
            float dist = sqrtf(fmaxf(d2, 1e-12f));
            if (labj == labs[r]) ap[r] = fmaxf(ap[r], dist);
            else an[r] = fminf(an[r], dist);
        }
    }
#pragma unroll
    for (int r = 0; r < 8; ++r) {
        for (int o = 32; o >= 1; o >>= 1) {
            ap[r] = fmaxf(ap[r], __shfl_xor(ap[r], o));
            an[r] = fminf(an[r], __shfl_xor(an[r], o));
        }
    }
    int wid = tid >> 6;
    if ((tid & 63) == 0) {
#pragma unroll
        for (int r = 0; r < 8; ++r) { red_ap[r][wid] = ap[r]; red_an[r][wid] = an[r]; }
    }
    __syncthreads();
    if (tid < 8) {
        float a = -INFINITY, n = INFINITY;
#pragma unroll
        for (int w = 0; w < 4; ++w) { a = fmaxf(a, red_ap[tid][w]); n = fminf(n, red_an[tid][w]); }
        a = fmaxf(a, 0.f);
        int* apbits = (int*)(ws + 2 * B);
        int* anbits = (int*)(ws + 3 * B);
        atomicMax(&apbits[row0 + tid], __float_as_int(a));
        atomicMin(&anbits[row0 + tid], __float_as_int(n));
    }
}

// ===== 256x128xBK32 GEMM, 3 blocks/CU (LDS-limited), 1 barrier/phase =====
// IDENTICAL schedule to R14 (passed correctness); only launch_bounds changed
// (256,3)->(256,2): R14's min-3-waves clamp capped VGPR at 84 and spilled the
// 128-reg accumulator to scratch (WRITE_SIZE 1.4GB). With the natural ~112 VGPR
// allocation: no spills; occupancy = LDS-limited = 3 blocks/CU (48KB each).
__global__ __launch_bounds__(256, 2) void ce_gemm_r3(const unsigned short* __restrict__ xp,
                                                     const float* __restrict__ W,
                                                     const float* __restrict__ bias,
                                                     float* __restrict__ ws) {
    const int b = blockIdx.x;
    const int xcd = b & 7, slot = b >> 3;
    const int cp = (slot >> 2) * 8 + xcd;   // column panel (128 cols)
    const int mb = slot & 3;                // row block (256 rows)
    if (cp >= NCP) return;
    const int rowbase = mb * 256;
    const int cbase = cp * 128;

    __shared__ unsigned short lds[24576];   // 48KB: A slots s*8192 (s=0,1); B at 16384 + p*4096

    const int tid = threadIdx.x;
    const int lane = tid & 63;
    const int wid = tid >> 6;
    const int wm = wid >> 1, wn = wid & 1;  // wave tile 128 rows x 64 cols
    const int q = lane >> 4, l15 = lane & 15;

    // B staging geometry: thread -> (col-class rB, 16-float half)
    const int rB = tid >> 1;
    const int ku0 = (tid & 1) * 2;
    const int swB = (rB >> 1) & 3;
    const int p0 = rB * 4 + (ku0 ^ swB);
    const int p1 = rB * 4 + ((ku0 + 1) ^ swB);
    int rc = cbase + rB; rc = rc < KC ? rc : KC - 1;
    const float* pW = W + (size_t)rc * D + (tid & 1) * 16;

    f32x4 acc[8][4];
#pragma unroll
    for (int m = 0; m < 8; ++m)
#pragma unroll
        for (int n = 0; n < 4; ++n) acc[m][n] = (f32x4){0.f, 0.f, 0.f, 0.f};

    f32x4 bsv[3][4];   // 3 reg-sets x 16 floats (static indexing via unrolled kt)

#define BLOAD(s_, kt_) {                                                           \
        _Pragma("unroll") for (int j = 0; j < 4; ++j)                              \
            bsv[s_][j] = *(const f32x4*)(pW + (kt_) * 32 + j * 4);                 \
        FENCE; }
#define ALOAD(kt_) {                                                               \
        const unsigned short* ga = xp + (size_t)(mb * 16 + (kt_)) * 8192;          \
        unsigned short* lA = &lds[((kt_) & 1) * 8192];                             \
        _Pragma("unroll") for (int i = 0; i < 4; ++i)                              \
            async16(ga + (i * 256 + tid) * 8, lA + (i * 256 + tid) * 8);           \
        FENCE; }
#define BCVW(s_, kt_) {                                                            \
        unsigned short* lB = &lds[16384 + ((kt_) & 1) * 4096];                     \
        unsigned u0[4] = { cvtpk(bsv[s_][0][0], bsv[s_][0][1]),                    \
                           cvtpk(bsv[s_][0][2], bsv[s_][0][3]),                    \
                           cvtpk(bsv[s_][1][0], bsv[s_][1][1]),                    \
                           cvtpk(bsv[s_][1][2], bsv[s_][1][3]) };                  \
        unsigned u1[4] = { cvtpk(bsv[s_][2][0], bsv[s_][2][1]),                    \
                           cvtpk(bsv[s_][2][2], bsv[s_][2][3]),                    \
                           cvtpk(bsv[s_][3][0], bsv[s_][3][1]),                    \
                           cvtpk(bsv[s_][3][2], bsv[s_][3][3]) };                  \
        *(uint4*)&lB[p0 * 8] = *(uint4*)u0;                                        \
        *(uint4*)&lB[p1 * 8] = *(uint4*)u1; }

    // prologue: A(0); B regs 0..2; wait A0+B0; write B(0) parity 0
    ALOAD(0);
    BLOAD(0, 0); BLOAD(1, 1); BLOAD(2, 2);
    VMCNT(8);             // in-order: A0,B0 complete (B1,B2 may float)
    BCVW(0, 0);
    LGKM0;

    bf16x8 af[4], bfr[4];
#pragma unroll
    for (int kt = 0; kt < 16; ++kt) {
        if (kt == 0) { VMCNT(8); } else if (kt <= 13) { VMCNT(4); } else { VMCNT(0); }
        __builtin_amdgcn_s_barrier(); FENCE;

        // issue next-phase loads immediately (max issue-to-wait distance)
        if (kt <= 14) ALOAD(kt + 1);
        if (kt <= 12) BLOAD((kt + 3) % 3, kt + 3);

        const unsigned short* sA = &lds[(kt & 1) * 8192];
        const unsigned short* sB = &lds[16384 + (kt & 1) * 4096];
#pragma unroll
        for (int n = 0; n < 4; ++n) {
            int rl = wn * 64 + n * 16 + l15;
            bfr[n] = *(const bf16x8*)&sB[(rl * 4 + (q ^ ((rl >> 1) & 3))) * 8];
        }
#pragma unroll
        for (int mg = 0; mg < 2; ++mg) {
#pragma unroll
            for (int mf = 0; mf < 4; ++mf) {
                int rl = wm * 128 + (mg * 4 + mf) * 16 + l15;
                af[mf] = *(const bf16x8*)&sA[(rl * 4 + (q ^ ((rl >> 1) & 3))) * 8];
            }
            __builtin_amdgcn_s_setprio(1);
#pragma unroll
            for (int mf = 0; mf < 4; ++mf)
#pragma unroll
                for (int n = 0; n < 4; ++n)
                    acc[mg * 4 + mf][n] = __builtin_amdgcn_mfma_f32_16x16x32_bf16(
                        af[mf], bfr[n], acc[mg * 4 + mf][n], 0, 0, 0);
            __builtin_amdgcn_s_setprio(0);
        }

        if (kt <= 14) BCVW((kt + 1) % 3, kt + 1);   // write next B into opposite parity
        LGKM0;                                      // ds_writes visible before next barrier
    }
#undef BLOAD
#undef ALOAD
#undef BCVW

    // ---- epilogue: per-row sum(exp)/sum(logit); shfl over l15; [256][2] LDS; atomics ----
    __syncthreads();
    float* redE = (float*)lds;           // [256][2]
    float* redL = redE + 512;            // [256][2]
    float biasv[4];
#pragma unroll
    for (int n = 0; n < 4; ++n) {
        int cc = cbase + wn * 64 + n * 16 + l15;
        biasv[n] = bias[cc < KC ? cc : KC - 1];
    }
#pragma unroll
    for (int m = 0; m < 8; ++m) {
#pragma unroll
        for (int r2 = 0; r2 < 4; ++r2) {
            float pe = 0.f, pl = 0.f;
#pragma unroll
            for (int n = 0; n < 4; ++n) {
                int cc = cbase + wn * 64 + n * 16 + l15;
                if (cc < KC) {
                    float lg = acc[m][n][r2] + biasv[n];
                    pe += __expf(lg);
                    pl += lg;
                }
            }
#pragma unroll
            for (int o = 1; o < 16; o <<= 1) {
                pe += __shfl_xor(pe, o);
                pl += __shfl_xor(pl, o);
            }
            if (l15 == 0) {
                int rowl = wm * 128 + m * 16 + q * 4 + r2;
                redE[rowl * 2 + wn] = pe;
                redL[rowl * 2 + wn] = pl;
            }
        }
    }
    __syncthreads();
    if (tid < 256) {
        float se = redE[tid * 2] + redE[tid * 2 + 1];
        float sl = redL[tid * 2] + redL[tid * 2 + 1];
        atomicAdd(&ws[rowbase + tid], se);
        atomicAdd(&ws[B + rowbase + tid], (EPSSM / (float)KC) * sl);
    }
}

// ---------------- final combine ----------------
__global__ __launch_bounds__(1024) void final_kernel(const float* __restrict__ ws,
                                                     float* __restrict__ out) {
    const float* sumexp = ws;
    const float* lin = ws + B;
    const int* apbits = (const int*)(ws + 2 * B);
    const int* anbits = (const int*)(ws + 3 * B);
    int i = threadIdx.x;
    float ce = logf(sumexp[i]) - lin[i];
    float ap = __int_as_float(apbits[i]);
    float an = __int_as_float(anbits[i]);
    float v = ce + fmaxf(ap - an + MARGIN, 0.f);
    for (int o = 32; o >= 1; o >>= 1) v += __shfl_xor(v, o);
    __shared__ float red[16];
    int wid = threadIdx.x >> 6, lane = threadIdx.x & 63;
    if (lane == 0) red[wid] = v;
    __syncthreads();
    if (threadIdx.x == 0) {
        float s = 0.f;
#pragma unroll
        for (int w = 0; w < 16; ++w) s += red[w];
        out[0] = s / (float)B;
    }
}

extern "C" void kernel_launch(void* const* d_in, const int* in_sizes, int n_in,
                              void* d_out, int out_size, void* d_ws, size_t ws_size,
                              hipStream_t stream) {
    const float* x = (const float*)d_in[0];
    const float* W = (const float*)d_in[1];
    const float* bias = (const float*)d_in[2];
    const int* labels = (const int*)d_in[3];
    float* out = (float*)d_out;
    float* ws = (float*)d_ws;

    unsigned short* xp = (unsigned short*)((char*)d_ws + 16384);   // 1MB packed x

    init_ws<<<16, 256, 0, stream>>>(ws);
    prep_kernel<<<768, 256, 0, stream>>>(x, W, bias, labels, ws, xp);
    ce_gemm_r3<<<8 * (NCP_PAD / 8) * 4, 256, 0, stream>>>(xp, W, bias, ws);
    final_kernel<<<1, 1024, 0, stream>>>(ws, out);
}

// Round 16
// 219.315 us; speedup vs baseline: 3.2383x; 1.0300x over previous
//
#include <hip/hip_runtime.h>
#include <hip/hip_bf16.h>
#include <math.h>

#define B 1024
#define D 512
#define KC 100000
#define MARGIN 0.3f
#define EPSSM 0.1f
#define NCP 782          // ceil(KC/128) column panels
#define NCP_PAD 784

typedef __attribute__((ext_vector_type(8))) short bf16x8;
typedef __attribute__((ext_vector_type(4))) float f32x4;

__device__ __forceinline__ unsigned cvtpk(float lo, float hi) {
    union { __hip_bfloat162 h2; unsigned u; } cv;
    cv.h2 = __float22bfloat162_rn(make_float2(lo, hi));
    return cv.u;
}

__device__ __forceinline__ void async16(const void* g, void* l) {
    __builtin_amdgcn_global_load_lds((const __attribute__((address_space(1))) unsigned int*)g,
                                     (__attribute__((address_space(3))) unsigned int*)l,
                                     16, 0, 0);
}

#define VMCNT(n) asm volatile("s_waitcnt vmcnt(" #n ")" ::: "memory")
#define LGKM0    asm volatile("s_waitcnt lgkmcnt(0)" ::: "memory")
#define FENCE    asm volatile("" ::: "memory")

// ws float layout: [0,B) sumexp | [B,2B) lin | [2B,3B) apbits | [3B,4B) anbits
// xp (packed bf16 x) at byte 16384: 64 regions x 16KB = 1MB.

__global__ void init_ws(float* ws) {
    int i = blockIdx.x * blockDim.x + threadIdx.x;
    if (i < 2 * B) ws[i] = 0.f;
    else if (i < 3 * B) ((int*)ws)[i] = 0;
    else if (i < 4 * B) ((int*)ws)[i] = 0x7F800000;
}

// ===== PREP: triplet[0,256) + tlabel[256,512) + pack_x[512,768) =====
__global__ __launch_bounds__(256) void prep_kernel(const float* __restrict__ x,
                                                   const float* __restrict__ W,
                                                   const float* __restrict__ bias,
                                                   const int* __restrict__ labels,
                                                   float* __restrict__ ws,
                                                   unsigned short* __restrict__ xp) {
    const int bid = blockIdx.x;
    const int tid = threadIdx.x;
    __shared__ float xs[8][D];
    __shared__ int labs[8];
    __shared__ float sqi[8];
    __shared__ float red_ap[8][4], red_an[8][4];

    if (bid >= 512) {
        // pack_x: region (mb*16+kt) = 16KB = [256 rows][4 units of 8 bf16],
        // data unit ku stored at pos qpos = ku ^ ((rloc>>1)&3)  (baked swizzle)
        int gid = (bid - 512) * 256 + tid;       // 64 regions * 1024 units
        int region = gid >> 10;
        int p = gid & 1023;
        int rloc = p >> 2, qpos = p & 3;
        int ku = qpos ^ ((rloc >> 1) & 3);
        int mb = region >> 4, kt = region & 15;
        const float* src = x + (size_t)(mb * 256 + rloc) * D + kt * 32 + ku * 8;
        f32x4 a = *(const f32x4*)src;
        f32x4 b2 = *(const f32x4*)(src + 4);
        unsigned pv[4] = { cvtpk(a[0], a[1]), cvtpk(a[2], a[3]), cvtpk(b2[0], b2[1]), cvtpk(b2[2], b2[3]) };
        *(uint4*)(xp + (size_t)region * 8192 + (size_t)p * 8) = *(uint4*)pv;
        return;
    }
    if (bid >= 256) {
        // tlabel -> lin += 0.9*(x.Wlab + blab)
        int wid = tid >> 6, lane = tid & 63;
        int row = (bid - 256) * 4 + wid;
        int lab = labels[row];
        const float* xr = x + (size_t)row * D;
        const float* wr = W + (size_t)lab * D;
        float dsum = 0.f;
#pragma unroll
        for (int u = 0; u < 2; ++u) {
            int k = (lane * 2 + u) * 4;
            float4 a = *(const float4*)&xr[k];
            float4 w = *(const float4*)&wr[k];
            dsum += a.x * w.x + a.y * w.y + a.z * w.z + a.w * w.w;
        }
        for (int o = 32; o >= 1; o >>= 1) dsum += __shfl_xor(dsum, o);
        if (lane == 0) atomicAdd(&ws[B + row], (1.f - EPSSM) * (dsum + bias[lab]));
        return;
    }

    // triplet: batch-hard over a 512-j half, atomic bitwise max/min merge
    const int row0 = (bid >> 1) * 8;
    const int jbase = (bid & 1) * 512;
    for (int f = tid; f < 8 * (D / 4); f += 256) {
        int r = f / (D / 4);
        int p = f % (D / 4);
        *(float4*)&xs[r][p * 4] = *(const float4*)&x[(size_t)(row0 + r) * D + p * 4];
    }
    if (tid < 8) labs[tid] = labels[row0 + tid];
    __syncthreads();
    if (tid < 8) {
        float s = 0.f;
        for (int k = 0; k < D; ++k) s += xs[tid][k] * xs[tid][k];
        sqi[tid] = s;
    }
    __syncthreads();

    float ap[8], an[8];
#pragma unroll
    for (int r = 0; r < 8; ++r) { ap[r] = -INFINITY; an[r] = INFINITY; }

    for (int j = jbase + tid; j < jbase + 512; j += 256) {
        int labj = labels[j];
        float dot[8];
        float sqj = 0.f;
#pragma unroll
        for (int r = 0; r < 8; ++r) dot[r] = 0.f;
        for (int kc = 0; kc < D; kc += 32) {
            float4 xj[8];
#pragma unroll
            for (int u = 0; u < 8; ++u) xj[u] = *(const float4*)&x[(size_t)j * D + kc + u * 4];
#pragma unroll
            for (int u = 0; u < 8; ++u)
                sqj += xj[u].x * xj[u].x + xj[u].y * xj[u].y + xj[u].z * xj[u].z + xj[u].w * xj[u].w;
#pragma unroll
            for (int r = 0; r < 8; ++r) {
                float d = 0.f;
#pragma unroll
                for (int u = 0; u < 8; ++u) {
                    const float4 a = *(const float4*)&xs[r][kc + u * 4];
                    d += a.x * xj[u].x + a.y * xj[u].y + a.z * xj[u].z + a.w * xj[u].w;
                }
                dot[r] += d;
            }
        }
#pragma unroll
        for (int r = 0; r < 8; ++r) {
            float d2 = sqi[r] + sqj - 2.f * dot[r];
            float dist = sqrtf(fmaxf(d2, 1e-12f));
            if (labj == labs[r]) ap[r] = fmaxf(ap[r], dist);
            else an[r] = fminf(an[r], dist);
        }
    }
#pragma unroll
    for (int r = 0; r < 8; ++r) {
        for (int o = 32; o >= 1; o >>= 1) {
            ap[r] = fmaxf(ap[r], __shfl_xor(ap[r], o));
            an[r] = fminf(an[r], __shfl_xor(an[r], o));
        }
    }
    int wid = tid >> 6;
    if ((tid & 63) == 0) {
#pragma unroll
        for (int r = 0; r < 8; ++r) { red_ap[r][wid] = ap[r]; red_an[r][wid] = an[r]; }
    }
    __syncthreads();
    if (tid < 8) {
        float a = -INFINITY, n = INFINITY;
#pragma unroll
        for (int w = 0; w < 4; ++w) { a = fmaxf(a, red_ap[tid][w]); n = fminf(n, red_an[tid][w]); }
        a = fmaxf(a, 0.f);
        int* apbits = (int*)(ws + 2 * B);
        int* anbits = (int*)(ws + 3 * B);
        atomicMax(&apbits[row0 + tid], __float_as_int(a));
        atomicMin(&anbits[row0 + tid], __float_as_int(n));
    }
}

// ===== 256x128xBK32 GEMM: A gload_lds (3-slot, linear src), B reg-staged from fp32 W =====
// R13 verbatim (session best: gemm 209us, total 219us, 0 conflicts, no spills).
// 256 thr, 4 waves (2Mx2N; wave tile 128x64). A: 3 x 16KB LDS slots. B: coalesced
// dwordx4 -> 3 reg-sets -> cvtpk -> swizzled ds_write into opposite B-parity (2x8KB).
// Ledger (issue order per phase: B(kt+3) then A(kt+2)): steady VMCNT(8); kt=14: 4; 15: 0.
__global__ __launch_bounds__(256, 2) void ce_gemm_r(const unsigned short* __restrict__ xp,
                                                    const float* __restrict__ W,
                                                    const float* __restrict__ bias,
                                                    float* __restrict__ ws) {
    const int b = blockIdx.x;
    const int xcd = b & 7, slot = b >> 3;
    const int cp = (slot >> 2) * 8 + xcd;   // column panel (128 cols)
    const int mb = slot & 3;                // row block (256 rows)
    if (cp >= NCP) return;
    const int rowbase = mb * 256;
    const int cbase = cp * 128;

    __shared__ unsigned short lds[32768];   // 64KB: A slots s*8192 (s=0..2), B par 24576+p*4096

    const int tid = threadIdx.x;
    const int lane = tid & 63;
    const int wid = tid >> 6;
    const int wm = wid >> 1, wn = wid & 1;  // wave tile 128 rows x 64 cols
    const int q = lane >> 4, l15 = lane & 15;

    // B staging geometry: thread -> (col-class rB, 16-float half)
    const int rB = tid >> 1;
    const int ku0 = (tid & 1) * 2;
    const int swB = (rB >> 1) & 3;
    const int p0 = rB * 4 + (ku0 ^ swB);
    const int p1 = rB * 4 + ((ku0 + 1) ^ swB);
    int rc = cbase + rB; rc = rc < KC ? rc : KC - 1;
    const float* pW = W + (size_t)rc * D + (tid & 1) * 16;

    f32x4 acc[8][4];
#pragma unroll
    for (int m = 0; m < 8; ++m)
#pragma unroll
        for (int n = 0; n < 4; ++n) acc[m][n] = (f32x4){0.f, 0.f, 0.f, 0.f};

    f32x4 bsv[3][4];   // 3 reg-sets x 16 floats

#define BLOAD(s_, kt_) {                                                           \
        _Pragma("unroll") for (int j = 0; j < 4; ++j)                              \
            bsv[s_][j] = *(const f32x4*)(pW + (kt_) * 32 + j * 4);                 \
        FENCE; }
#define ALOAD(kt_) {                                                               \
        const unsigned short* ga = xp + (size_t)(mb * 16 + (kt_)) * 8192;          \
        unsigned short* lA = &lds[((kt_) % 3) * 8192];                             \
        _Pragma("unroll") for (int i = 0; i < 4; ++i)                              \
            async16(ga + (i * 256 + tid) * 8, lA + (i * 256 + tid) * 8);           \
        FENCE; }
#define BCVW(s_, kt_) {                                                            \
        unsigned short* lB = &lds[24576 + ((kt_) & 1) * 4096];                     \
        unsigned u0[4] = { cvtpk(bsv[s_][0][0], bsv[s_][0][1]),                    \
                           cvtpk(bsv[s_][0][2], bsv[s_][0][3]),                    \
                           cvtpk(bsv[s_][1][0], bsv[s_][1][1]),                    \
                           cvtpk(bsv[s_][1][2], bsv[s_][1][3]) };                  \
        unsigned u1[4] = { cvtpk(bsv[s_][2][0], bsv[s_][2][1]),                    \
                           cvtpk(bsv[s_][2][2], bsv[s_][2][3]),                    \
                           cvtpk(bsv[s_][3][0], bsv[s_][3][1]),                    \
                           cvtpk(bsv[s_][3][2], bsv[s_][3][3]) };                  \
        *(uint4*)&lB[p0 * 8] = *(uint4*)u0;                                        \
        *(uint4*)&lB[p1 * 8] = *(uint4*)u1; }

    // prologue (ledger history): B0; B1; A0; B2; A1
    BLOAD(0, 0); BLOAD(1, 1); ALOAD(0); BLOAD(2, 2); ALOAD(1);
    VMCNT(16);            // B0 regs complete
    BCVW(0, 0);           // B(0) into parity 0
    LGKM0;

    bf16x8 af[4], bfr[4];
#pragma unroll
    for (int kt = 0; kt < 16; ++kt) {
        if (kt <= 13) { VMCNT(8); } else if (kt == 14) { VMCNT(4); } else { VMCNT(0); }
        __builtin_amdgcn_s_barrier(); FENCE;

        const unsigned short* sA = &lds[(kt % 3) * 8192];
        const unsigned short* sB = &lds[24576 + (kt & 1) * 4096];
#pragma unroll
        for (int n = 0; n < 4; ++n) {
            int rl = wn * 64 + n * 16 + l15;
            bfr[n] = *(const bf16x8*)&sB[(rl * 4 + (q ^ ((rl >> 1) & 3))) * 8];
        }
#pragma unroll
        for (int mg = 0; mg < 2; ++mg) {
#pragma unroll
            for (int mf = 0; mf < 4; ++mf) {
                int rl = wm * 128 + (mg * 4 + mf) * 16 + l15;
                af[mf] = *(const bf16x8*)&sA[(rl * 4 + (q ^ ((rl >> 1) & 3))) * 8];
            }
            __builtin_amdgcn_s_setprio(1);
#pragma unroll
            for (int mf = 0; mf < 4; ++mf)
#pragma unroll
                for (int n = 0; n < 4; ++n)
                    acc[mg * 4 + mf][n] = __builtin_amdgcn_mfma_f32_16x16x32_bf16(
                        af[mf], bfr[n], acc[mg * 4 + mf][n], 0, 0, 0);
            __builtin_amdgcn_s_setprio(0);
        }

        if (kt < 15) BCVW((kt + 1) % 3, kt + 1);   // write next B into opposite parity
        if (kt <= 12) BLOAD((kt + 3) % 3, kt + 3); // issue order: B first...
        if (kt <= 13) ALOAD(kt + 2);               // ...then A (ledger invariant)
        LGKM0;                                     // B ds_writes visible before barrier
        __builtin_amdgcn_s_barrier(); FENCE;
    }
#undef BLOAD
#undef ALOAD
#undef BCVW

    // ---- epilogue: per-row sum(exp)/sum(logit); shfl over l15; [256][2] LDS; atomics ----
    __syncthreads();
    float* redE = (float*)lds;           // [256][2]
    float* redL = redE + 512;            // [256][2]
    float biasv[4];
#pragma unroll
    for (int n = 0; n < 4; ++n) {
        int cc = cbase + wn * 64 + n * 16 + l15;
        biasv[n] = bias[cc < KC ? cc : KC - 1];
    }
#pragma unroll
    for (int m = 0; m < 8; ++m) {
#pragma unroll
        for (int r2 = 0; r2 < 4; ++r2) {
            float pe = 0.f, pl = 0.f;
#pragma unroll
            for (int n = 0; n < 4; ++n) {
                int cc = cbase + wn * 64 + n * 16 + l15;
                if (cc < KC) {
                    float lg = acc[m][n][r2] + biasv[n];
                    pe += __expf(lg);
                    pl += lg;
                }
            }
#pragma unroll
            for (int o = 1; o < 16; o <<= 1) {
                pe += __shfl_xor(pe, o);
                pl += __shfl_xor(pl, o);
            }
            if (l15 == 0) {
                int rowl = wm * 128 + m * 16 + q * 4 + r2;
                redE[rowl * 2 + wn] = pe;
                redL[rowl * 2 + wn] = pl;
            }
        }
    }
    __syncthreads();
    if (tid < 256) {
        float se = redE[tid * 2] + redE[tid * 2 + 1];
        float sl = redL[tid * 2] + redL[tid * 2 + 1];
        atomicAdd(&ws[rowbase + tid], se);
        atomicAdd(&ws[B + rowbase + tid], (EPSSM / (float)KC) * sl);
    }
}

// ---------------- final combine ----------------
__global__ __launch_bounds__(1024) void final_kernel(const float* __restrict__ ws,
                                                     float* __restrict__ out) {
    const float* sumexp = ws;
    const float* lin = ws + B;
    const int* apbits = (const int*)(ws + 2 * B);
    const int* anbits = (const int*)(ws + 3 * B);
    int i = threadIdx.x;
    float ce = logf(sumexp[i]) - lin[i];
    float ap = __int_as_float(apbits[i]);
    float an = __int_as_float(anbits[i]);
    float v = ce + fmaxf(ap - an + MARGIN, 0.f);
    for (int o = 32; o >= 1; o >>= 1) v += __shfl_xor(v, o);
    __shared__ float red[16];
    int wid = threadIdx.x >> 6, lane = threadIdx.x & 63;
    if (lane == 0) red[wid] = v;
    __syncthreads();
    if (threadIdx.x == 0) {
        float s = 0.f;
#pragma unroll
        for (int w = 0; w < 16; ++w) s += red[w];
        out[0] = s / (float)B;
    }
}

extern "C" void kernel_launch(void* const* d_in, const int* in_sizes, int n_in,
                              void* d_out, int out_size, void* d_ws, size_t ws_size,
                              hipStream_t stream) {
    const float* x = (const float*)d_in[0];
    const float* W = (const float*)d_in[1];
    const float* bias = (const float*)d_in[2];
    const int* labels = (const int*)d_in[3];
    float* out = (float*)d_out;
    float* ws = (float*)d_ws;

    unsigned short* xp = (unsigned short*)((char*)d_ws + 16384);   // 1MB packed x

    init_ws<<<16, 256, 0, stream>>>(ws);
    prep_kernel<<<768, 256, 0, stream>>>(x, W, bias, labels, ws, xp);
    ce_gemm_r<<<8 * (NCP_PAD / 8) * 4, 256, 0, stream>>>(xp, W, bias, ws);
    final_kernel<<<1, 1024, 0, stream>>>(ws, out);
}